// Round 5
// baseline (41.234 us; speedup 1.0000x reference)
//
#include <hip/hip_runtime.h>
#include <math.h>

// Problem constants: inputs (128, 64, 64, 32) fp32
#define BB 128
#define NN 64
#define DD 2048            // 64*32
#define NBLK 256           // one block per (batch, column-half)
#define NTHR 1024          // 16 waves

__device__ __forceinline__ float wave_reduce_sum(float v) {
    #pragma unroll
    for (int off = 32; off > 0; off >>= 1)
        v += __shfl_down(v, off, 64);
    return v;
}

// Block u -> batch b = (u&7)|((u>>4)<<3), half h = (u>>3)&1.
// Siblings (u, u+8) land on the same XCD under round-robin dispatch, so the
// duplicated phase-A read of the batch mostly L2-hits.
__global__ __launch_bounds__(NTHR) void fused_loss_kernel(
        const float* __restrict__ x,
        double* __restrict__ partials,
        unsigned* __restrict__ counter,
        float* __restrict__ out) {
    const unsigned u = blockIdx.x;
    const int b = (int)((u & 7u) | ((u >> 4) << 3));
    const int h = (int)((u >> 3) & 1u);
    const int t = threadIdx.x;
    const int lane = t & 63, wid = t >> 6;     // 16 waves

    __shared__ float invs[NN];
    __shared__ float diag_w[16];
    __shared__ float red[16];
    __shared__ int is_last;
    __shared__ double sd[NBLK];

    const float* xb = x + (size_t)b * NN * DD;

    // ---- Phase A: all 64 row norms (wave w -> rows 4w..4w+3) ----
    float diag = 0.f;
    #pragma unroll
    for (int rr = 0; rr < 4; ++rr) {
        const int row = wid * 4 + rr;
        const float4* p = reinterpret_cast<const float4*>(xb + (size_t)row * DD);
        float s = 0.f;
        #pragma unroll
        for (int j = 0; j < 8; ++j) {          // 512 float4 per row
            float4 a = p[lane + 64 * j];
            s += a.x * a.x + a.y * a.y + a.z * a.z + a.w * a.w;
        }
        s = wave_reduce_sum(s);
        if (lane == 0) {
            float r = fmaxf(sqrtf(s), 1e-12f);
            float inv = 1.0f / r;
            invs[row] = inv;
            diag += s * inv * inv;             // ||att_row||^2
        }
    }
    // only the h==0 sibling contributes the diag term (avoid double count)
    if (lane == 0) diag_w[wid] = (h == 0) ? diag : 0.f;
    __syncthreads();

    // ---- Phase B: thread t owns column h*1024 + t; v = sum_n x[n][d]*inv[n] ----
    {
        const float* xc = xb + h * 1024 + t;
        float v0 = 0.f, v1 = 0.f;              // 2 chains for ILP
        #pragma unroll 8
        for (int n = 0; n < NN; n += 2) {
            v0 = fmaf(xc[(size_t)n * DD],       invs[n],     v0);
            v1 = fmaf(xc[(size_t)(n + 1) * DD], invs[n + 1], v1);
        }
        const float v = v0 + v1;
        float p = v * v;
        p = wave_reduce_sum(p);
        if (lane == 0) red[wid] = p;
    }
    __syncthreads();

    if (t == 0) {
        double sp = 0.0, dp = 0.0;
        #pragma unroll
        for (int w = 0; w < 16; ++w) { sp += (double)red[w]; dp += (double)diag_w[w]; }
        __hip_atomic_store(&partials[u], sp - dp,
                           __ATOMIC_RELEASE, __HIP_MEMORY_SCOPE_AGENT);
        unsigned old = __hip_atomic_fetch_add(counter, 1u,
                                              __ATOMIC_ACQ_REL, __HIP_MEMORY_SCOPE_AGENT);
        is_last = (old == NBLK - 1) ? 1 : 0;
    }
    __syncthreads();

    // ---- Last block: deterministic fixed-order tree sum of 256 partials ----
    if (is_last) {
        if (t < NBLK)
            sd[t] = __hip_atomic_load(&partials[t],
                                      __ATOMIC_RELAXED, __HIP_MEMORY_SCOPE_AGENT);
        __syncthreads();
        #pragma unroll
        for (int off = NBLK / 2; off > 0; off >>= 1) {
            if (t < off) sd[t] += sd[t + off];
            __syncthreads();
        }
        if (t == 0) out[0] = (float)(sd[0] / (double)BB);
    }
}

extern "C" void kernel_launch(void* const* d_in, const int* in_sizes, int n_in,
                              void* d_out, int out_size, void* d_ws, size_t ws_size,
                              hipStream_t stream) {
    const float* x = (const float*)d_in[0];
    float* out = (float*)d_out;

    double* partials = (double*)d_ws;                       // 256 doubles = 2 KB
    unsigned* counter = (unsigned*)((char*)d_ws + 2048);    // 4 bytes

    hipMemsetAsync(counter, 0, sizeof(unsigned), stream);   // graph-capturable
    fused_loss_kernel<<<NBLK, NTHR, 0, stream>>>(x, partials, counter, out);
}